// Round 1
// 69.474 us; speedup vs baseline: 1.0068x; 1.0068x over previous
//
#include <hip/hip_runtime.h>
#include <hip/hip_bf16.h>
#include <math.h>

// S4D as batched GEMM.  out[h, i*64+j] = 2*Re( sum_n Cc'[h,n] * W[h,n]^i * q[h,n]^j )
// with W = exp(dtA*64), q = exp(dtA).  Per h this is a real 64x64x64 matmul:
//   A[i][k]  : k=n -> Re(Cc'*W^i), k=32+n -> -Im(Cc'*W^i)      (64 x 64)
//   B[k][j]  : k=n -> Re(q^j),     k=32+n ->  Im(q^j)           (64 x 64)
//   out_tile = 2 * A*B
// MFMA 16x16x32 bf16 with hi/lo split (Ah*Bh + Ah*Bl + Al*Bh): abs err ~2e-3
// << 3.06e-2 threshold.
//
// R1 change: latency attack.  Previous version: 256 thr/block, 4 waves/SIMD,
// ~15% issue utilization (kernel ~27.5us vs ~4us of issue work).  Now 512
// thr/block (8 waves): gen phase is 4 modes/thread (half the serial chain),
// MFMA phase splits each 16-row band across 2 waves (12 MFMA/wave).  LDS
// unchanged (37.6KB -> 4 blocks = 2048 thr/CU, HW max).  floor+sub -> v_fract.

typedef __bf16 bf16x4 __attribute__((ext_vector_type(4)));
typedef __bf16 bf16x8 __attribute__((ext_vector_type(8)));
typedef float  f32x4  __attribute__((ext_vector_type(4)));

constexpr int H_  = 1024;
constexpr int N2_ = 32;
constexpr int L_  = 4096;
constexpr int BT_ = 512;
constexpr int KP_ = 72;   // padded K stride in bf16 elems

__global__ __launch_bounds__(BT_, 4) void s4d_kernel(
    const float* __restrict__ log_dt,
    const float* __restrict__ C,
    const float* __restrict__ log_A_real,
    const float* __restrict__ A_imag,
    float* __restrict__ out)
{
    __shared__ __bf16 Ah[64][KP_], Al[64][KP_];   // A hi/lo   (i  x k)
    __shared__ __bf16 Bh[64][KP_], Bl[64][KP_];   // B^T hi/lo (j  x k)
    __shared__ float sCre[N2_], sCim[N2_];        // Cc'
    __shared__ float sAl2[N2_];                   // dtar*log2e      (per-step mag)
    __shared__ float sRho1[N2_];                  // fract(dtai/2pi) (per-step phase)
    __shared__ float sM64[N2_];                   // dtar*64*log2e   (per-64-step mag)
    __shared__ float sRho64[N2_];                 // fract(64*dtai/2pi)

    const int h = blockIdx.x;
    const int t = threadIdx.x;
    const float L2E = 1.442695040888963f;

    if (t < N2_) {
        const int n = t;
        const float dt   = __builtin_amdgcn_exp2f(log_dt[h] * L2E);
        const float ar   = -__builtin_amdgcn_exp2f(log_A_real[h * N2_ + n] * L2E);
        const float ai   = A_imag[h * N2_ + n];
        const float dtar = ar * dt;
        const float dtai = ai * dt;

        // Cc' = Cc * (e^{dtA}-1)/A
        const float em  = __builtin_amdgcn_exp2f(dtar * L2E);
        const float efr = __builtin_amdgcn_fractf(dtai * 0.15915494309189535f);
        const float ere = em * __builtin_amdgcn_cosf(efr) - 1.0f;
        const float eim = em * __builtin_amdgcn_sinf(efr);
        const float cre = C[(h * N2_ + n) * 2 + 0];
        const float cim = C[(h * N2_ + n) * 2 + 1];
        const float inv = 1.0f / (ar * ar + ai * ai);
        const float qre = (ere * ar + eim * ai) * inv;
        const float qim = (eim * ar - ere * ai) * inv;
        sCre[n] = cre * qre - cim * qim;
        sCim[n] = cre * qim + cim * qre;

        sAl2[n] = dtar * L2E;
        sM64[n] = dtar * (64.0f * L2E);
        // phase reductions mod 1 revolution in fp64 (only place fp64 is needed)
        const double rho = (double)dtai * 0.15915494309189535;
        sRho1[n]  = (float)(rho - floor(rho));
        const double r64 = rho * 64.0;
        sRho64[n] = (float)(r64 - floor(r64));
    }
    __syncthreads();

    // ---- generate A (row = i) and B^T (row = j), 4 modes per thread ----
    {
        const int row = t >> 3;          // 0..63 : i for A, j for B
        const int n0  = (t & 7) * 4;     // modes n0..n0+3
        const float rf = (float)row;
        __bf16 hRe[4], lRe[4], hIm[4], lIm[4];
        __bf16 gRe[4], mRe[4], gIm[4], mIm[4];

        #pragma unroll
        for (int qi = 0; qi < 4; qi++) {
            const int n = n0 + qi;
            // A: Cc' * W^row
            {
                const float mag = __builtin_amdgcn_exp2f(sM64[n] * rf);
                const float ph  = __builtin_amdgcn_fractf(sRho64[n] * rf);
                const float c = __builtin_amdgcn_cosf(ph);
                const float s = __builtin_amdgcn_sinf(ph);
                const float wre = mag * c, wim = mag * s;
                const float are = sCre[n] * wre - sCim[n] * wim;
                const float aim = sCre[n] * wim + sCim[n] * wre;
                const float nim = -aim;
                const __bf16 h1 = (__bf16)are; hRe[qi] = h1; lRe[qi] = (__bf16)(are - (float)h1);
                const __bf16 h2 = (__bf16)nim; hIm[qi] = h2; lIm[qi] = (__bf16)(nim - (float)h2);
            }
            // B: q^row
            {
                const float mag = __builtin_amdgcn_exp2f(sAl2[n] * rf);
                const float ph  = __builtin_amdgcn_fractf(sRho1[n] * rf);
                const float c = __builtin_amdgcn_cosf(ph);
                const float s = __builtin_amdgcn_sinf(ph);
                const float bre = mag * c, bim = mag * s;
                const __bf16 h1 = (__bf16)bre; gRe[qi] = h1; mRe[qi] = (__bf16)(bre - (float)h1);
                const __bf16 h2 = (__bf16)bim; gIm[qi] = h2; mIm[qi] = (__bf16)(bim - (float)h2);
            }
        }
        *(bf16x4*)&Ah[row][n0]      = (bf16x4){hRe[0], hRe[1], hRe[2], hRe[3]};
        *(bf16x4*)&Ah[row][32 + n0] = (bf16x4){hIm[0], hIm[1], hIm[2], hIm[3]};
        *(bf16x4*)&Al[row][n0]      = (bf16x4){lRe[0], lRe[1], lRe[2], lRe[3]};
        *(bf16x4*)&Al[row][32 + n0] = (bf16x4){lIm[0], lIm[1], lIm[2], lIm[3]};
        *(bf16x4*)&Bh[row][n0]      = (bf16x4){gRe[0], gRe[1], gRe[2], gRe[3]};
        *(bf16x4*)&Bh[row][32 + n0] = (bf16x4){gIm[0], gIm[1], gIm[2], gIm[3]};
        *(bf16x4*)&Bl[row][n0]      = (bf16x4){mRe[0], mRe[1], mRe[2], mRe[3]};
        *(bf16x4*)&Bl[row][32 + n0] = (bf16x4){mIm[0], mIm[1], mIm[2], mIm[3]};
    }
    __syncthreads();

    // ---- MFMA: wave wv owns rows [16*(wv>>1), +16) x cols [32*(wv&1), +32) ----
    const int wv   = t >> 6;
    const int lid  = t & 63;
    const int lo16 = lid & 15;
    const int q4   = lid >> 4;
    const int band = wv >> 1;
    const int ntb  = (wv & 1) * 2;
    const int mrow = band * 16 + lo16;

    f32x4 acc[2] = {f32x4{0,0,0,0}, f32x4{0,0,0,0}};

    #pragma unroll
    for (int kt = 0; kt < 2; kt++) {
        const int kk = kt * 32 + q4 * 8;
        const bf16x8 af = *(const bf16x8*)&Ah[mrow][kk];
        const bf16x8 al = *(const bf16x8*)&Al[mrow][kk];
        #pragma unroll
        for (int u = 0; u < 2; u++) {
            const int nt = ntb + u;
            const bf16x8 bf = *(const bf16x8*)&Bh[nt * 16 + lo16][kk];
            const bf16x8 bl = *(const bf16x8*)&Bl[nt * 16 + lo16][kk];
            acc[u] = __builtin_amdgcn_mfma_f32_16x16x32_bf16(af, bf, acc[u], 0, 0, 0);
            acc[u] = __builtin_amdgcn_mfma_f32_16x16x32_bf16(af, bl, acc[u], 0, 0, 0);
            acc[u] = __builtin_amdgcn_mfma_f32_16x16x32_bf16(al, bf, acc[u], 0, 0, 0);
        }
    }

    // ---- epilogue: D[row=(q4*4+r)][col=lo16] per tile; l = i*64 + j ----
    float* op = out + (size_t)h * L_;
    #pragma unroll
    for (int u = 0; u < 2; u++) {
        const int j = (ntb + u) * 16 + lo16;
        #pragma unroll
        for (int r = 0; r < 4; r++) {
            const int i = band * 16 + q4 * 4 + r;
            op[i * 64 + j] = 2.0f * acc[u][r];
        }
    }
}

extern "C" void kernel_launch(void* const* d_in, const int* in_sizes, int n_in,
                              void* d_out, int out_size, void* d_ws, size_t ws_size,
                              hipStream_t stream) {
    const float* log_dt     = (const float*)d_in[1];
    const float* C          = (const float*)d_in[2];
    const float* log_A_real = (const float*)d_in[3];
    const float* A_imag     = (const float*)d_in[4];
    float* out = (float*)d_out;
    (void)d_ws; (void)ws_size;

    s4d_kernel<<<dim3(H_), dim3(BT_), 0, stream>>>(log_dt, C, log_A_real, A_imag, out);
}